// Round 9
// baseline (682.753 us; speedup 1.0000x reference)
//
#include <hip/hip_runtime.h>

#define IN_HW 512
#define OUT_HW 1024
#define NB 32
#define NC 3
#define TOH 64          // output tile rows (2 row-pairs per thread)
#define TOW 128
#define NTHREADS 256

typedef float  f32x4 __attribute__((ext_vector_type(4)));
typedef int    i32x4 __attribute__((ext_vector_type(4)));

// ---------------- sortable-key encoding for f32 atomics ----------------------
__device__ __forceinline__ unsigned enc_f(float f) {
  unsigned u = __float_as_uint(f);
  return (u & 0x80000000u) ? ~u : (u | 0x80000000u);
}
__device__ __forceinline__ float dec_f(unsigned k) {
  unsigned u = (k & 0x80000000u) ? (k ^ 0x80000000u) : ~k;
  return __uint_as_float(u);
}

// ---------------- hardcoded normalized Lanczos4 2x-upsample weights ----------
// Derived in f64: w(d)=sinc(d)sinc(d/4), phases d=3.75-j (even) / 3.25-j (odd),
// normalized to sum 1. Max abs error ~2e-6 -> output perturbation ~0.05 u8
// levels; cannot change absmax class.
#define LW_A -0.00397053f  /* |d|=3.75 */
#define LW_B  0.03146474f  /* |d|=2.75 */
#define LW_C -0.09165979f  /* |d|=1.75 */
#define LW_D  0.28268104f  /* |d|=0.75 */
#define LW_E  0.89337959f  /* |d|=0.25 */
#define LW_F -0.15228947f  /* |d|=1.25 */
#define LW_G  0.05544842f  /* |d|=2.25 */
#define LW_H -0.01505400f  /* |d|=3.25 */

// ---------------- kernel 0: init min/max key slots (ws is poisoned) ----------
__global__ void k_init(unsigned* __restrict__ maxk, unsigned* __restrict__ mink) {
  int i = threadIdx.x;
  if (i < NB) maxk[i] = 0u;
  else if (i < 2 * NB) mink[i - NB] = 0xFFFFFFFFu;
}

// ---------------- vertical accumulate: 10 input rows -> 4 vert rows ----------
// Thread covers out rows {4p..4p+3} = row-pairs A (base k) and B (base k+1),
// k = oh0/2 + 2p. Input rows k-4..k+5 (j=0..9). Each loaded quad feeds up to
// 4 accumulator chains.
//   vAe: j=0..7  w0[j]   (out row 4p)      vAo: j=1..8  w1[j-1] (out row 4p+1)
//   vBe: j=1..8  w0[j-1] (out row 4p+2)    vBo: j=2..9  w1[j-2] (out row 4p+3)
__device__ __forceinline__ void vert_accum(
    const f32x4 a, const f32x4 b, const f32x4 c, int j,
    const float w0[8], const float w1[8],
    float vAe[12], float vAo[12], float vBe[12], float vBo[12]) {
  const float tv[12] = {a.x, a.y, a.z, a.w, b.x, b.y, b.z, b.w,
                        c.x, c.y, c.z, c.w};
#pragma unroll
  for (int cc = 0; cc < 12; ++cc) {
    if (j < 8)           vAe[cc] = fmaf(w0[j],     tv[cc], vAe[cc]);
    if (j >= 1 && j < 9) vAo[cc] = fmaf(w1[j - 1], tv[cc], vAo[cc]);
    if (j >= 1 && j < 9) vBe[cc] = fmaf(w0[j - 1], tv[cc], vBe[cc]);
    if (j >= 2)          vBo[cc] = fmaf(w1[j - 2], tv[cc], vBo[cc]);
  }
}

// horizontal: even out col 8o+2m taps v[m..m+7] (w0); odd taps v[m+1..m+8] (w1)
__device__ __forceinline__ void horiz8(
    const float v[12], const float w0[8], const float w1[8], float px[8]) {
#pragma unroll
  for (int m = 0; m < 4; ++m) {
    float pe = 0.f, po = 0.f;
#pragma unroll
    for (int j = 0; j < 8; ++j) {
      pe = fmaf(w0[j], v[m + j], pe);
      po = fmaf(w1[j], v[m + 1 + j], po);
    }
    px[2 * m] = pe; px[2 * m + 1] = po;
  }
}

// -------- kernel 1: resize ONCE -> f32 spill to out + per-image min/max ------
// Full 30-load batch + sched_barrier(0): R6 showed plain batched arrays get
// load-sunk by LLVM (VGPR stayed 84, no effect); R8's depth-2 pipeline (3 in
// flight) gave 315->235us. The fence forbids FMA hoisting above the loads ->
// ~30 outstanding loads/wave. Costs VGPR (~2 waves/SIMD) but per-SIMD MLP
// rises 12 -> ~60; compiler still emits progressive vmcnt waits.
// Single-arg launch_bounds: R7's (256,4) forced VGPR=64 -> scratch spill.
__global__ __launch_bounds__(NTHREADS) void k_resize(
    const float* __restrict__ x, float* __restrict__ outf,
    unsigned* __restrict__ maxk, unsigned* __restrict__ mink) {
  __shared__ float wred[8];
  const int tid = threadIdx.x;
  const int bc = blockIdx.z;
  const int oh0 = blockIdx.y * TOH, ow0 = blockIdx.x * TOW;
  const float* __restrict__ xchan = x + (size_t)bc * (IN_HW * IN_HW);
  const int o = tid & 15;            // col octet: out cols ow0+8o..+7
  const int p = tid >> 4;            // 0..15: out rows oh0+4p..+3
  const int k = (oh0 >> 1) + 2 * p;  // even-row base
  const int rowbase = k - 4;         // input rows rowbase..rowbase+9
  const int qb = ((ow0 >> 1) - 4) >> 2;   // quad base (can be -1)
  const int q0 = qb + o;

  const float w0[8] = {LW_A, LW_B, LW_C, LW_D, LW_E, LW_F, LW_G, LW_H};
  const float w1[8] = {LW_H, LW_G, LW_F, LW_E, LW_D, LW_C, LW_B, LW_A};

  float vAe[12], vAo[12], vBe[12], vBo[12];
#pragma unroll
  for (int c = 0; c < 12; ++c) { vAe[c] = vAo[c] = vBe[c] = vBo[c] = 0.f; }

  const bool fast = (blockIdx.x > 0) & (blockIdx.x < 7) &
                    (blockIdx.y > 0) & (blockIdx.y < (OUT_HW / TOH) - 1);
  if (fast) {
    const float* __restrict__ tp = xchan + (size_t)rowbase * IN_HW + 4 * q0;
    f32x4 t[10][3];
#pragma unroll
    for (int j = 0; j < 10; ++j) {
      t[j][0] = *reinterpret_cast<const f32x4*>(tp + (size_t)j * IN_HW);
      t[j][1] = *reinterpret_cast<const f32x4*>(tp + (size_t)j * IN_HW + 4);
      t[j][2] = *reinterpret_cast<const f32x4*>(tp + (size_t)j * IN_HW + 8);
    }
    __builtin_amdgcn_sched_barrier(0);   // no FMA above this line: batch issue
#pragma unroll
    for (int j = 0; j < 10; ++j)
      vert_accum(t[j][0], t[j][1], t[j][2], j, w0, w1, vAe, vAo, vBe, vBo);
  } else {
    // border: row clamp + column splat (quad -1 -> col 0, quad 128 -> col 511)
#pragma unroll
    for (int j = 0; j < 10; ++j) {
      int gr = rowbase + j;
      gr = gr < 0 ? 0 : (gr > IN_HW - 1 ? IN_HW - 1 : gr);
      const float* __restrict__ rowp = xchan + ((size_t)gr << 9);
      f32x4 t[3];
#pragma unroll
      for (int g = 0; g < 3; ++g) {
        const int q = q0 + g;
        const int qc = q < 0 ? 0 : (q > IN_HW / 4 - 1 ? IN_HW / 4 - 1 : q);
        f32x4 v = reinterpret_cast<const f32x4*>(rowp)[qc];
        if (q < 0)             { float e = rowp[0];         v = (f32x4){e, e, e, e}; }
        if (q > IN_HW / 4 - 1) { float e = rowp[IN_HW - 1]; v = (f32x4){e, e, e, e}; }
        t[g] = v;
      }
      vert_accum(t[0], t[1], t[2], j, w0, w1, vAe, vAo, vBe, vBo);
    }
  }

  // horizontal + spill + minmax, one output row at a time (regs reused)
  const size_t base = (size_t)bc * (OUT_HW * OUT_HW) +
                      (size_t)(oh0 + 4 * p) * OUT_HW + (ow0 + 8 * o);
  float mx = -__builtin_inff(), mn = __builtin_inff();
#pragma unroll
  for (int r = 0; r < 4; ++r) {
    const float* v = (r == 0) ? vAe : (r == 1) ? vAo : (r == 2) ? vBe : vBo;
    float px[8];
    horiz8(v, w0, w1, px);
#pragma unroll
    for (int i = 0; i < 8; ++i) { mx = fmaxf(mx, px[i]); mn = fminf(mn, px[i]); }
    float* dst = outf + base + (size_t)r * OUT_HW;
    *reinterpret_cast<f32x4*>(dst)     = (f32x4){px[0], px[1], px[2], px[3]};
    *reinterpret_cast<f32x4*>(dst + 4) = (f32x4){px[4], px[5], px[6], px[7]};
  }

  // block min/max: wave shuffle reduce, then cross-wave via LDS
#pragma unroll
  for (int s = 32; s > 0; s >>= 1) {
    mx = fmaxf(mx, __shfl_xor(mx, s, 64));
    mn = fminf(mn, __shfl_xor(mn, s, 64));
  }
  if ((tid & 63) == 0) { wred[tid >> 6] = mx; wred[4 + (tid >> 6)] = mn; }
  __syncthreads();
  if (tid == 0) {
    float bmx = fmaxf(fmaxf(wred[0], wred[1]), fmaxf(wred[2], wred[3]));
    float bmn = fminf(fminf(wred[4], wred[5]), fminf(wred[6], wred[7]));
    int b = bc / NC;
    atomicMax(&maxk[b], enc_f(bmx));
    atomicMin(&mink[b], enc_f(bmn));
  }
}

// ---------------- kernel 2: in-place renorm f32 -> saturating int32 ----------
// NT load (no reuse); PLAIN store (R6: NT 16B stores inflate WRITE_SIZE 40%).
__device__ __forceinline__ int renorm1(float img, bool applies, float cA, float cB,
                                       float om_ott, float om_ubt) {
  const float ott = 1.0f / 255.0f;
  const float ubt = -10.0f / 255.0f;
  float v1 = (img > 1.0f) ? fmaf(img - 1.0f, cA, 1.0f - ott)
           : (img < 1.0f) ? img * om_ott : img;
  float v2 = (v1 < 0.0f) ? fmaf(v1, cB, ubt)
           : (v1 > 0.0f) ? v1 * om_ubt : v1;
  float y = (applies ? v2 : img) * 255.0f;
  int t = (int)y;                       // XLA f32->u8: trunc toward zero
  return t < 0 ? 0 : (t > 255 ? 255 : t);
}

#define N4_PER_IMG (NC * OUT_HW * OUT_HW / 4)   // 786432 float4 per image

__global__ __launch_bounds__(NTHREADS) void k_renorm(
    int* out, const unsigned* __restrict__ maxk, const unsigned* __restrict__ mink) {
  const int b = blockIdx.y;
  const float mx = dec_f(maxk[b]);
  const float mn = dec_f(mink[b]);
  const bool applies = (mx - mn) > 1.0f;
  const float ott = 1.0f / 255.0f;
  const float ubt = -10.0f / 255.0f;
  const float otr = mx - 1.0f;
  const float cA = ott / ((otr != 0.0f) ? otr : 1.0f);
  const float cB = ubt / ((mn != 0.0f) ? mn : 1.0f);
  const float om_ott = 1.0f - ott;
  const float om_ubt = 1.0f - ubt;

  const size_t idx = (size_t)b * N4_PER_IMG +
                     (size_t)blockIdx.x * NTHREADS + threadIdx.x;
  const f32x4 v = __builtin_nontemporal_load(
      reinterpret_cast<const f32x4*>(out) + idx);
  i32x4 r;
  r.x = renorm1(v.x, applies, cA, cB, om_ott, om_ubt);
  r.y = renorm1(v.y, applies, cA, cB, om_ott, om_ubt);
  r.z = renorm1(v.z, applies, cA, cB, om_ott, om_ubt);
  r.w = renorm1(v.w, applies, cA, cB, om_ott, om_ubt);
  reinterpret_cast<i32x4*>(out)[idx] = r;
}

extern "C" void kernel_launch(void* const* d_in, const int* in_sizes, int n_in,
                              void* d_out, int out_size, void* d_ws, size_t ws_size,
                              hipStream_t stream) {
  const float* x = (const float*)d_in[0];
  unsigned* maxk = (unsigned*)d_ws;
  unsigned* mink = maxk + NB;

  hipLaunchKernelGGL(k_init, dim3(1), dim3(64), 0, stream, maxk, mink);
  dim3 grid(OUT_HW / TOW, OUT_HW / TOH, NB * NC);
  hipLaunchKernelGGL(k_resize, grid, dim3(NTHREADS), 0, stream,
                     x, (float*)d_out, maxk, mink);
  hipLaunchKernelGGL(k_renorm, dim3(N4_PER_IMG / NTHREADS, NB), dim3(NTHREADS),
                     0, stream, (int*)d_out, maxk, mink);
}

// Round 10
// 664.853 us; speedup vs baseline: 1.0269x; 1.0269x over previous
//
#include <hip/hip_runtime.h>

#define IN_HW 512
#define OUT_HW 1024
#define NB 32
#define NC 3
#define TOH 64          // output tile rows (2 row-pairs per thread)
#define TOW 128
#define NTHREADS 256

typedef float  f32x4 __attribute__((ext_vector_type(4)));
typedef int    i32x4 __attribute__((ext_vector_type(4)));

// ---------------- sortable-key encoding for f32 atomics ----------------------
__device__ __forceinline__ unsigned enc_f(float f) {
  unsigned u = __float_as_uint(f);
  return (u & 0x80000000u) ? ~u : (u | 0x80000000u);
}
__device__ __forceinline__ float dec_f(unsigned k) {
  unsigned u = (k & 0x80000000u) ? (k ^ 0x80000000u) : ~k;
  return __uint_as_float(u);
}

// ---------------- hardcoded normalized Lanczos4 2x-upsample weights ----------
// Derived in f64: w(d)=sinc(d)sinc(d/4), phases d=3.75-j (even) / 3.25-j (odd),
// normalized to sum 1. Max abs error ~2e-6 -> output perturbation ~0.05 u8
// levels; cannot change absmax class.
#define LW_A -0.00397053f  /* |d|=3.75 */
#define LW_B  0.03146474f  /* |d|=2.75 */
#define LW_C -0.09165979f  /* |d|=1.75 */
#define LW_D  0.28268104f  /* |d|=0.75 */
#define LW_E  0.89337959f  /* |d|=0.25 */
#define LW_F -0.15228947f  /* |d|=1.25 */
#define LW_G  0.05544842f  /* |d|=2.25 */
#define LW_H -0.01505400f  /* |d|=3.25 */

// ---------------- kernel 0: init min/max key slots (ws is poisoned) ----------
__global__ void k_init(unsigned* __restrict__ maxk, unsigned* __restrict__ mink) {
  int i = threadIdx.x;
  if (i < NB) maxk[i] = 0u;
  else if (i < 2 * NB) mink[i - NB] = 0xFFFFFFFFu;
}

// ---------------- vertical accumulate: 10 input rows -> 4 vert rows ----------
// Thread covers out rows {4p..4p+3} = row-pairs A (base k) and B (base k+1),
// k = oh0/2 + 2p. Input rows k-4..k+5 (j=0..9). Each loaded quad feeds up to
// 4 accumulator chains.
//   vAe: j=0..7  w0[j]   (out row 4p)      vAo: j=1..8  w1[j-1] (out row 4p+1)
//   vBe: j=1..8  w0[j-1] (out row 4p+2)    vBo: j=2..9  w1[j-2] (out row 4p+3)
__device__ __forceinline__ void vert_accum(
    const f32x4 a, const f32x4 b, const f32x4 c, int j,
    const float w0[8], const float w1[8],
    float vAe[12], float vAo[12], float vBe[12], float vBo[12]) {
  const float tv[12] = {a.x, a.y, a.z, a.w, b.x, b.y, b.z, b.w,
                        c.x, c.y, c.z, c.w};
#pragma unroll
  for (int cc = 0; cc < 12; ++cc) {
    if (j < 8)           vAe[cc] = fmaf(w0[j],     tv[cc], vAe[cc]);
    if (j >= 1 && j < 9) vAo[cc] = fmaf(w1[j - 1], tv[cc], vAo[cc]);
    if (j >= 1 && j < 9) vBe[cc] = fmaf(w0[j - 1], tv[cc], vBe[cc]);
    if (j >= 2)          vBo[cc] = fmaf(w1[j - 2], tv[cc], vBo[cc]);
  }
}

// horizontal: even out col 8o+2m taps v[m..m+7] (w0); odd taps v[m+1..m+8] (w1)
__device__ __forceinline__ void horiz8(
    const float v[12], const float w0[8], const float w1[8], float px[8]) {
#pragma unroll
  for (int m = 0; m < 4; ++m) {
    float pe = 0.f, po = 0.f;
#pragma unroll
    for (int j = 0; j < 8; ++j) {
      pe = fmaf(w0[j], v[m + j], pe);
      po = fmaf(w1[j], v[m + 1 + j], po);
    }
    px[2 * m] = pe; px[2 * m + 1] = po;
  }
}

// -------- kernel 1: resize ONCE -> f32 spill to out + per-image min/max ------
// Depth-3 ring pipeline (4 slots): row j+3's 3 loads issue at top of iter j,
// so each row's loads get ~3 rows of FMAs (~210cy) of latency cover vs ~225cy
// L2 latency. R8's depth-2 (1 row, ~70cy) = 235us; R9's 30-deep fence = ~260us
// (VGPR cost > MLP gain). This sits between at ~120 VGPR / 4 waves per SIMD.
// Single-arg launch_bounds: R7's (256,4) forced VGPR=64 -> scratch spill.
__global__ __launch_bounds__(NTHREADS) void k_resize(
    const float* __restrict__ x, float* __restrict__ outf,
    unsigned* __restrict__ maxk, unsigned* __restrict__ mink) {
  __shared__ float wred[8];
  const int tid = threadIdx.x;
  const int bc = blockIdx.z;
  const int oh0 = blockIdx.y * TOH, ow0 = blockIdx.x * TOW;
  const float* __restrict__ xchan = x + (size_t)bc * (IN_HW * IN_HW);
  const int o = tid & 15;            // col octet: out cols ow0+8o..+7
  const int p = tid >> 4;            // 0..15: out rows oh0+4p..+3
  const int k = (oh0 >> 1) + 2 * p;  // even-row base
  const int rowbase = k - 4;         // input rows rowbase..rowbase+9
  const int qb = ((ow0 >> 1) - 4) >> 2;   // quad base (can be -1)
  const int q0 = qb + o;

  const float w0[8] = {LW_A, LW_B, LW_C, LW_D, LW_E, LW_F, LW_G, LW_H};
  const float w1[8] = {LW_H, LW_G, LW_F, LW_E, LW_D, LW_C, LW_B, LW_A};

  float vAe[12], vAo[12], vBe[12], vBo[12];
#pragma unroll
  for (int c = 0; c < 12; ++c) { vAe[c] = vAo[c] = vBe[c] = vBo[c] = 0.f; }

  const bool fast = (blockIdx.x > 0) & (blockIdx.x < 7) &
                    (blockIdx.y > 0) & (blockIdx.y < (OUT_HW / TOH) - 1);
  if (fast) {
    const float* __restrict__ tp = xchan + (size_t)rowbase * IN_HW + 4 * q0;
    f32x4 t[4][3];                      // ring: slot = row % 4
#pragma unroll
    for (int j = 0; j < 3; ++j) {       // prologue: rows 0..2 -> slots 0..2
      t[j][0] = *reinterpret_cast<const f32x4*>(tp + (size_t)j * IN_HW);
      t[j][1] = *reinterpret_cast<const f32x4*>(tp + (size_t)j * IN_HW + 4);
      t[j][2] = *reinterpret_cast<const f32x4*>(tp + (size_t)j * IN_HW + 8);
    }
#pragma unroll
    for (int j = 0; j < 10; ++j) {
      if (j + 3 < 10) {                 // issue row j+3 into slot (j+3)&3
        const int s = (j + 3) & 3;
        const float* __restrict__ np = tp + (size_t)(j + 3) * IN_HW;
        t[s][0] = *reinterpret_cast<const f32x4*>(np);
        t[s][1] = *reinterpret_cast<const f32x4*>(np + 4);
        t[s][2] = *reinterpret_cast<const f32x4*>(np + 8);
      }
      const int sj = j & 3;
      vert_accum(t[sj][0], t[sj][1], t[sj][2], j, w0, w1, vAe, vAo, vBe, vBo);
    }
  } else {
    // border: row clamp + column splat (quad -1 -> col 0, quad 128 -> col 511)
#pragma unroll
    for (int j = 0; j < 10; ++j) {
      int gr = rowbase + j;
      gr = gr < 0 ? 0 : (gr > IN_HW - 1 ? IN_HW - 1 : gr);
      const float* __restrict__ rowp = xchan + ((size_t)gr << 9);
      f32x4 t[3];
#pragma unroll
      for (int g = 0; g < 3; ++g) {
        const int q = q0 + g;
        const int qc = q < 0 ? 0 : (q > IN_HW / 4 - 1 ? IN_HW / 4 - 1 : q);
        f32x4 v = reinterpret_cast<const f32x4*>(rowp)[qc];
        if (q < 0)             { float e = rowp[0];         v = (f32x4){e, e, e, e}; }
        if (q > IN_HW / 4 - 1) { float e = rowp[IN_HW - 1]; v = (f32x4){e, e, e, e}; }
        t[g] = v;
      }
      vert_accum(t[0], t[1], t[2], j, w0, w1, vAe, vAo, vBe, vBo);
    }
  }

  // horizontal + spill + minmax, one output row at a time (regs reused)
  const size_t base = (size_t)bc * (OUT_HW * OUT_HW) +
                      (size_t)(oh0 + 4 * p) * OUT_HW + (ow0 + 8 * o);
  float mx = -__builtin_inff(), mn = __builtin_inff();
#pragma unroll
  for (int r = 0; r < 4; ++r) {
    const float* v = (r == 0) ? vAe : (r == 1) ? vAo : (r == 2) ? vBe : vBo;
    float px[8];
    horiz8(v, w0, w1, px);
#pragma unroll
    for (int i = 0; i < 8; ++i) { mx = fmaxf(mx, px[i]); mn = fminf(mn, px[i]); }
    float* dst = outf + base + (size_t)r * OUT_HW;
    *reinterpret_cast<f32x4*>(dst)     = (f32x4){px[0], px[1], px[2], px[3]};
    *reinterpret_cast<f32x4*>(dst + 4) = (f32x4){px[4], px[5], px[6], px[7]};
  }

  // block min/max: wave shuffle reduce, then cross-wave via LDS
#pragma unroll
  for (int s = 32; s > 0; s >>= 1) {
    mx = fmaxf(mx, __shfl_xor(mx, s, 64));
    mn = fminf(mn, __shfl_xor(mn, s, 64));
  }
  if ((tid & 63) == 0) { wred[tid >> 6] = mx; wred[4 + (tid >> 6)] = mn; }
  __syncthreads();
  if (tid == 0) {
    float bmx = fmaxf(fmaxf(wred[0], wred[1]), fmaxf(wred[2], wred[3]));
    float bmn = fminf(fminf(wred[4], wred[5]), fminf(wred[6], wred[7]));
    int b = bc / NC;
    atomicMax(&maxk[b], enc_f(bmx));
    atomicMin(&mink[b], enc_f(bmn));
  }
}

// ---------------- kernel 2: in-place renorm f32 -> saturating int32 ----------
// PLAIN load: the 384MB spill was just written and largely sits in the 256MB
// L3 -- an NT read bypasses those hits (R9 structure). PLAIN store (R6: NT 16B
// stores inflate WRITE_SIZE 40%).
__device__ __forceinline__ int renorm1(float img, bool applies, float cA, float cB,
                                       float om_ott, float om_ubt) {
  const float ott = 1.0f / 255.0f;
  const float ubt = -10.0f / 255.0f;
  float v1 = (img > 1.0f) ? fmaf(img - 1.0f, cA, 1.0f - ott)
           : (img < 1.0f) ? img * om_ott : img;
  float v2 = (v1 < 0.0f) ? fmaf(v1, cB, ubt)
           : (v1 > 0.0f) ? v1 * om_ubt : v1;
  float y = (applies ? v2 : img) * 255.0f;
  int t = (int)y;                       // XLA f32->u8: trunc toward zero
  return t < 0 ? 0 : (t > 255 ? 255 : t);
}

#define N4_PER_IMG (NC * OUT_HW * OUT_HW / 4)   // 786432 float4 per image

__global__ __launch_bounds__(NTHREADS) void k_renorm(
    int* out, const unsigned* __restrict__ maxk, const unsigned* __restrict__ mink) {
  const int b = blockIdx.y;
  const float mx = dec_f(maxk[b]);
  const float mn = dec_f(mink[b]);
  const bool applies = (mx - mn) > 1.0f;
  const float ott = 1.0f / 255.0f;
  const float ubt = -10.0f / 255.0f;
  const float otr = mx - 1.0f;
  const float cA = ott / ((otr != 0.0f) ? otr : 1.0f);
  const float cB = ubt / ((mn != 0.0f) ? mn : 1.0f);
  const float om_ott = 1.0f - ott;
  const float om_ubt = 1.0f - ubt;

  const size_t idx = (size_t)b * N4_PER_IMG +
                     (size_t)blockIdx.x * NTHREADS + threadIdx.x;
  const f32x4 v = reinterpret_cast<const f32x4*>(out)[idx];
  i32x4 r;
  r.x = renorm1(v.x, applies, cA, cB, om_ott, om_ubt);
  r.y = renorm1(v.y, applies, cA, cB, om_ott, om_ubt);
  r.z = renorm1(v.z, applies, cA, cB, om_ott, om_ubt);
  r.w = renorm1(v.w, applies, cA, cB, om_ott, om_ubt);
  reinterpret_cast<i32x4*>(out)[idx] = r;
}

extern "C" void kernel_launch(void* const* d_in, const int* in_sizes, int n_in,
                              void* d_out, int out_size, void* d_ws, size_t ws_size,
                              hipStream_t stream) {
  const float* x = (const float*)d_in[0];
  unsigned* maxk = (unsigned*)d_ws;
  unsigned* mink = maxk + NB;

  hipLaunchKernelGGL(k_init, dim3(1), dim3(64), 0, stream, maxk, mink);
  dim3 grid(OUT_HW / TOW, OUT_HW / TOH, NB * NC);
  hipLaunchKernelGGL(k_resize, grid, dim3(NTHREADS), 0, stream,
                     x, (float*)d_out, maxk, mink);
  hipLaunchKernelGGL(k_renorm, dim3(N4_PER_IMG / NTHREADS, NB), dim3(NTHREADS),
                     0, stream, (int*)d_out, maxk, mink);
}

// Round 11
// 655.198 us; speedup vs baseline: 1.0421x; 1.0147x over previous
//
#include <hip/hip_runtime.h>

#define IN_HW 512
#define OUT_HW 1024
#define NB 32
#define NC 3
#define TOH 64          // output tile rows (2 row-pairs per thread)
#define TOW 128
#define NTHREADS 256

typedef float  f32x4 __attribute__((ext_vector_type(4)));
typedef int    i32x4 __attribute__((ext_vector_type(4)));

// ---------------- sortable-key encoding for f32 atomics ----------------------
__device__ __forceinline__ unsigned enc_f(float f) {
  unsigned u = __float_as_uint(f);
  return (u & 0x80000000u) ? ~u : (u | 0x80000000u);
}
__device__ __forceinline__ float dec_f(unsigned k) {
  unsigned u = (k & 0x80000000u) ? (k ^ 0x80000000u) : ~k;
  return __uint_as_float(u);
}

// ---------------- hardcoded normalized Lanczos4 2x-upsample weights ----------
// Derived in f64: w(d)=sinc(d)sinc(d/4), phases d=3.75-j (even) / 3.25-j (odd),
// normalized to sum 1. Max abs error ~2e-6 -> output perturbation ~0.05 u8
// levels; cannot change absmax class.
#define LW_A -0.00397053f  /* |d|=3.75 */
#define LW_B  0.03146474f  /* |d|=2.75 */
#define LW_C -0.09165979f  /* |d|=1.75 */
#define LW_D  0.28268104f  /* |d|=0.75 */
#define LW_E  0.89337959f  /* |d|=0.25 */
#define LW_F -0.15228947f  /* |d|=1.25 */
#define LW_G  0.05544842f  /* |d|=2.25 */
#define LW_H -0.01505400f  /* |d|=3.25 */

// ---------------- kernel 0: init min/max key slots (ws is poisoned) ----------
__global__ void k_init(unsigned* __restrict__ maxk, unsigned* __restrict__ mink) {
  int i = threadIdx.x;
  if (i < NB) maxk[i] = 0u;
  else if (i < 2 * NB) mink[i - NB] = 0xFFFFFFFFu;
}

// ---------------- vertical accumulate: 10 input rows -> 4 vert rows ----------
// Thread covers out rows {4p..4p+3} = row-pairs A (base k) and B (base k+1),
// k = oh0/2 + 2p. Input rows k-4..k+5 (j=0..9). Each loaded quad feeds up to
// 4 accumulator chains.
//   vAe: j=0..7  w0[j]   (out row 4p)      vAo: j=1..8  w1[j-1] (out row 4p+1)
//   vBe: j=1..8  w0[j-1] (out row 4p+2)    vBo: j=2..9  w1[j-2] (out row 4p+3)
__device__ __forceinline__ void vert_accum(
    const f32x4 a, const f32x4 b, const f32x4 c, int j,
    const float w0[8], const float w1[8],
    float vAe[12], float vAo[12], float vBe[12], float vBo[12]) {
  const float tv[12] = {a.x, a.y, a.z, a.w, b.x, b.y, b.z, b.w,
                        c.x, c.y, c.z, c.w};
#pragma unroll
  for (int cc = 0; cc < 12; ++cc) {
    if (j < 8)           vAe[cc] = fmaf(w0[j],     tv[cc], vAe[cc]);
    if (j >= 1 && j < 9) vAo[cc] = fmaf(w1[j - 1], tv[cc], vAo[cc]);
    if (j >= 1 && j < 9) vBe[cc] = fmaf(w0[j - 1], tv[cc], vBe[cc]);
    if (j >= 2)          vBo[cc] = fmaf(w1[j - 2], tv[cc], vBo[cc]);
  }
}

// horizontal: even out col 8o+2m taps v[m..m+7] (w0); odd taps v[m+1..m+8] (w1)
__device__ __forceinline__ void horiz8(
    const float v[12], const float w0[8], const float w1[8], float px[8]) {
#pragma unroll
  for (int m = 0; m < 4; ++m) {
    float pe = 0.f, po = 0.f;
#pragma unroll
    for (int j = 0; j < 8; ++j) {
      pe = fmaf(w0[j], v[m + j], pe);
      po = fmaf(w1[j], v[m + 1 + j], po);
    }
    px[2 * m] = pe; px[2 * m + 1] = po;
  }
}

// -------- kernel 1: resize ONCE -> f32 spill to out + per-image min/max ------
// Depth-2 software pipeline: row j+1's 3 quads issue before row j's FMAs.
// Best measured structure (R8: 658us total, k_resize ~235us). Deeper pipelines
// (R9 30-deep fence, R10 depth-3 ring) measured null-to-negative: VGPR cost
// exceeds MLP gain past ~3 rows in flight at 4 waves/SIMD.
// Single-arg launch_bounds: R7's (256,4) forced VGPR=64 -> scratch spill.
__global__ __launch_bounds__(NTHREADS) void k_resize(
    const float* __restrict__ x, float* __restrict__ outf,
    unsigned* __restrict__ maxk, unsigned* __restrict__ mink) {
  __shared__ float wred[8];
  const int tid = threadIdx.x;
  const int bc = blockIdx.z;
  const int oh0 = blockIdx.y * TOH, ow0 = blockIdx.x * TOW;
  const float* __restrict__ xchan = x + (size_t)bc * (IN_HW * IN_HW);
  const int o = tid & 15;            // col octet: out cols ow0+8o..+7
  const int p = tid >> 4;            // 0..15: out rows oh0+4p..+3
  const int k = (oh0 >> 1) + 2 * p;  // even-row base
  const int rowbase = k - 4;         // input rows rowbase..rowbase+9
  const int qb = ((ow0 >> 1) - 4) >> 2;   // quad base (can be -1)
  const int q0 = qb + o;

  const float w0[8] = {LW_A, LW_B, LW_C, LW_D, LW_E, LW_F, LW_G, LW_H};
  const float w1[8] = {LW_H, LW_G, LW_F, LW_E, LW_D, LW_C, LW_B, LW_A};

  float vAe[12], vAo[12], vBe[12], vBo[12];
#pragma unroll
  for (int c = 0; c < 12; ++c) { vAe[c] = vAo[c] = vBe[c] = vBo[c] = 0.f; }

  const bool fast = (blockIdx.x > 0) & (blockIdx.x < 7) &
                    (blockIdx.y > 0) & (blockIdx.y < (OUT_HW / TOH) - 1);
  if (fast) {
    // depth-2 software pipeline: row j+1's 3 quads issue before row j's FMAs
    const float* __restrict__ tp = xchan + (size_t)rowbase * IN_HW + 4 * q0;
    f32x4 a0 = *reinterpret_cast<const f32x4*>(tp);
    f32x4 b0 = *reinterpret_cast<const f32x4*>(tp + 4);
    f32x4 c0 = *reinterpret_cast<const f32x4*>(tp + 8);
#pragma unroll
    for (int j = 0; j < 10; ++j) {
      if (j < 9) {
        const float* __restrict__ np = tp + (size_t)(j + 1) * IN_HW;
        f32x4 a1 = *reinterpret_cast<const f32x4*>(np);
        f32x4 b1 = *reinterpret_cast<const f32x4*>(np + 4);
        f32x4 c1 = *reinterpret_cast<const f32x4*>(np + 8);
        vert_accum(a0, b0, c0, j, w0, w1, vAe, vAo, vBe, vBo);
        a0 = a1; b0 = b1; c0 = c1;
      } else {
        vert_accum(a0, b0, c0, j, w0, w1, vAe, vAo, vBe, vBo);
      }
    }
  } else {
    // border: row clamp + column splat (quad -1 -> col 0, quad 128 -> col 511)
#pragma unroll
    for (int j = 0; j < 10; ++j) {
      int gr = rowbase + j;
      gr = gr < 0 ? 0 : (gr > IN_HW - 1 ? IN_HW - 1 : gr);
      const float* __restrict__ rowp = xchan + ((size_t)gr << 9);
      f32x4 t[3];
#pragma unroll
      for (int g = 0; g < 3; ++g) {
        const int q = q0 + g;
        const int qc = q < 0 ? 0 : (q > IN_HW / 4 - 1 ? IN_HW / 4 - 1 : q);
        f32x4 v = reinterpret_cast<const f32x4*>(rowp)[qc];
        if (q < 0)             { float e = rowp[0];         v = (f32x4){e, e, e, e}; }
        if (q > IN_HW / 4 - 1) { float e = rowp[IN_HW - 1]; v = (f32x4){e, e, e, e}; }
        t[g] = v;
      }
      vert_accum(t[0], t[1], t[2], j, w0, w1, vAe, vAo, vBe, vBo);
    }
  }

  // horizontal + spill + minmax, one output row at a time (regs reused)
  const size_t base = (size_t)bc * (OUT_HW * OUT_HW) +
                      (size_t)(oh0 + 4 * p) * OUT_HW + (ow0 + 8 * o);
  float mx = -__builtin_inff(), mn = __builtin_inff();
#pragma unroll
  for (int r = 0; r < 4; ++r) {
    const float* v = (r == 0) ? vAe : (r == 1) ? vAo : (r == 2) ? vBe : vBo;
    float px[8];
    horiz8(v, w0, w1, px);
#pragma unroll
    for (int i = 0; i < 8; ++i) { mx = fmaxf(mx, px[i]); mn = fminf(mn, px[i]); }
    float* dst = outf + base + (size_t)r * OUT_HW;
    *reinterpret_cast<f32x4*>(dst)     = (f32x4){px[0], px[1], px[2], px[3]};
    *reinterpret_cast<f32x4*>(dst + 4) = (f32x4){px[4], px[5], px[6], px[7]};
  }

  // block min/max: wave shuffle reduce, then cross-wave via LDS
#pragma unroll
  for (int s = 32; s > 0; s >>= 1) {
    mx = fmaxf(mx, __shfl_xor(mx, s, 64));
    mn = fminf(mn, __shfl_xor(mn, s, 64));
  }
  if ((tid & 63) == 0) { wred[tid >> 6] = mx; wred[4 + (tid >> 6)] = mn; }
  __syncthreads();
  if (tid == 0) {
    float bmx = fmaxf(fmaxf(wred[0], wred[1]), fmaxf(wred[2], wred[3]));
    float bmn = fminf(fminf(wred[4], wred[5]), fminf(wred[6], wred[7]));
    int b = bc / NC;
    atomicMax(&maxk[b], enc_f(bmx));
    atomicMin(&mink[b], enc_f(bmn));
  }
}

// ---------------- kernel 2: in-place renorm f32 -> saturating int32 ----------
// NT load (no reuse); PLAIN store (R6: NT 16B stores inflate WRITE_SIZE 40%).
__device__ __forceinline__ int renorm1(float img, bool applies, float cA, float cB,
                                       float om_ott, float om_ubt) {
  const float ott = 1.0f / 255.0f;
  const float ubt = -10.0f / 255.0f;
  float v1 = (img > 1.0f) ? fmaf(img - 1.0f, cA, 1.0f - ott)
           : (img < 1.0f) ? img * om_ott : img;
  float v2 = (v1 < 0.0f) ? fmaf(v1, cB, ubt)
           : (v1 > 0.0f) ? v1 * om_ubt : v1;
  float y = (applies ? v2 : img) * 255.0f;
  int t = (int)y;                       // XLA f32->u8: trunc toward zero
  return t < 0 ? 0 : (t > 255 ? 255 : t);
}

#define N4_PER_IMG (NC * OUT_HW * OUT_HW / 4)   // 786432 float4 per image

__global__ __launch_bounds__(NTHREADS) void k_renorm(
    int* out, const unsigned* __restrict__ maxk, const unsigned* __restrict__ mink) {
  const int b = blockIdx.y;
  const float mx = dec_f(maxk[b]);
  const float mn = dec_f(mink[b]);
  const bool applies = (mx - mn) > 1.0f;
  const float ott = 1.0f / 255.0f;
  const float ubt = -10.0f / 255.0f;
  const float otr = mx - 1.0f;
  const float cA = ott / ((otr != 0.0f) ? otr : 1.0f);
  const float cB = ubt / ((mn != 0.0f) ? mn : 1.0f);
  const float om_ott = 1.0f - ott;
  const float om_ubt = 1.0f - ubt;

  const size_t idx = (size_t)b * N4_PER_IMG +
                     (size_t)blockIdx.x * NTHREADS + threadIdx.x;
  const f32x4 v = __builtin_nontemporal_load(
      reinterpret_cast<const f32x4*>(out) + idx);
  i32x4 r;
  r.x = renorm1(v.x, applies, cA, cB, om_ott, om_ubt);
  r.y = renorm1(v.y, applies, cA, cB, om_ott, om_ubt);
  r.z = renorm1(v.z, applies, cA, cB, om_ott, om_ubt);
  r.w = renorm1(v.w, applies, cA, cB, om_ott, om_ubt);
  reinterpret_cast<i32x4*>(out)[idx] = r;
}

extern "C" void kernel_launch(void* const* d_in, const int* in_sizes, int n_in,
                              void* d_out, int out_size, void* d_ws, size_t ws_size,
                              hipStream_t stream) {
  const float* x = (const float*)d_in[0];
  unsigned* maxk = (unsigned*)d_ws;
  unsigned* mink = maxk + NB;

  hipLaunchKernelGGL(k_init, dim3(1), dim3(64), 0, stream, maxk, mink);
  dim3 grid(OUT_HW / TOW, OUT_HW / TOH, NB * NC);
  hipLaunchKernelGGL(k_resize, grid, dim3(NTHREADS), 0, stream,
                     x, (float*)d_out, maxk, mink);
  hipLaunchKernelGGL(k_renorm, dim3(N4_PER_IMG / NTHREADS, NB), dim3(NTHREADS),
                     0, stream, (int*)d_out, maxk, mink);
}